// Round 1
// baseline (121.477 us; speedup 1.0000x reference)
//
#include <hip/hip_runtime.h>
#include <stdint.h>

// GLOM level-1 spatial-prior attention, fused.
// out[c,i] = sum_j e_ij*p_ij*x[c,j] / (sum_j e_ij*p_ij + 1e-8*sum_j e_ij),
// e_ij = exp(<xn_i, xn_j>)  (cosine sims in [-1,1] -> no softmax max needed).

#define HW    4096
#define CDIM  128
#define NBATCH 2
#define QT    32
#define KT    64
#define NT    (HW / KT)   // 64 key tiles

typedef float f32x4 __attribute__((ext_vector_type(4)));
typedef short s16x8 __attribute__((ext_vector_type(8)));

__device__ __forceinline__ unsigned short f2bf(float f) {
  unsigned u = __builtin_bit_cast(unsigned, f);
  u += 0x7fffu + ((u >> 16) & 1u);        // RNE (finite inputs only)
  return (unsigned short)(u >> 16);
}

__device__ __forceinline__ void stage16(const void* g, void* l) {
  __builtin_amdgcn_global_load_lds((const __attribute__((address_space(1))) void*)g,
                                   (__attribute__((address_space(3))) void*)l, 16, 0, 0);
}

// ---------------- prep: norms + bf16 casts ----------------
// writes xnT: (B, HW, C) bf16 normalized (QK operands)
//        xc : (B, C, HW) bf16 raw x      (PV B-operand, read direct from global)
__global__ __launch_bounds__(256) void prep_kernel(const float* __restrict__ x,
                                                   unsigned short* __restrict__ xnT,
                                                   unsigned short* __restrict__ xc) {
  __shared__ float ssq[4][64];
  __shared__ float rn[64];
  const int b  = blockIdx.x >> 6;          // 64 blocks per batch
  const int i0 = (blockIdx.x & 63) * 64;
  const int tid = threadIdx.x;
  const int p = tid & 63, g = tid >> 6;
  const float* xb = x + (size_t)b * CDIM * HW;

  float ss = 0.f;
#pragma unroll 4
  for (int k = 0; k < 32; ++k) {
    const int c = g * 32 + k;
    float v = xb[(size_t)c * HW + i0 + p];
    ss += v * v;
    xc[(size_t)(b * CDIM + c) * HW + i0 + p] = f2bf(v);
  }
  ssq[g][p] = ss;
  __syncthreads();
  if (tid < 64) {
    float s = ssq[0][tid] + ssq[1][tid] + ssq[2][tid] + ssq[3][tid];
    rn[tid] = 1.0f / fmaxf(sqrtf(s), 1e-12f);
  }
  __syncthreads();
  // pass 2: xnT rows (pos-major), 16B vector stores
  const int p2 = tid >> 2;
  const int cc = (tid & 3) * 32;
  const float r = rn[p2];
  unsigned short* dst = xnT + (size_t)(b * HW + i0 + p2) * CDIM + cc;
#pragma unroll
  for (int ch = 0; ch < 4; ++ch) {
    s16x8 o;
#pragma unroll
    for (int e = 0; e < 8; ++e) {
      float v = xb[(size_t)(cc + ch * 8 + e) * HW + i0 + p2];
      o[e] = (short)f2bf(v * r);
    }
    *(s16x8*)(dst + ch * 8) = o;
  }
}

// ---------------- fused attention ----------------
__global__ __launch_bounds__(512) void glom_attn_kernel(const float* __restrict__ probs,
                                                        const unsigned short* __restrict__ xnT,
                                                        const unsigned short* __restrict__ xc,
                                                        float* __restrict__ out) {
  __shared__ __align__(16) unsigned char kbuf[2][KT * CDIM * 2];  // 2 x 16KB, K tiles (swizzled)
  __shared__ __align__(16) unsigned char pbuf[QT * KT * 2];       // 4KB, P' tile (swizzled)
  __shared__ float zred[4][QT];
  __shared__ float prred[4][QT];
  __shared__ float denl[QT];

  const int tid = threadIdx.x;
  const int wv  = tid >> 6;
  const int l   = tid & 63;
  const int lhi = l >> 4, llo = l & 15;
  const int b   = blockIdx.x & 1;                 // batch-interleaved for probs reuse
  const int q0  = (int)(blockIdx.x >> 1) * QT;

  const int qf1 = wv >> 2, kf = wv & 3;           // phase-1 wave tile
  const int qf2 = wv & 1,  cf0 = (wv >> 1) * 2;   // phase-2 wave tile

  const unsigned short* xnTb = xnT + (size_t)b * HW * CDIM;
  const unsigned short* xcb  = xc  + (size_t)b * CDIM * HW;

  // Q hoist: A-frags (row = llo, k = lhi*8+e + kk*32)
  s16x8 aq[4];
  {
    const unsigned short* qp = xnTb + (size_t)(q0 + qf1 * 16 + llo) * CDIM + lhi * 8;
#pragma unroll
    for (int kk = 0; kk < 4; ++kk) aq[kk] = *(const s16x8*)(qp + kk * 32);
  }

  // staging: wave stages 2 x 1KB chunks; LDS linear dest, inverse-swizzled global src
  const int o0 = (2 * wv) * 1024 + l * 16;
  const int o1 = o0 + 1024;
  const int g0 = o0 ^ (((o0 >> 8) & 7) << 4);     // K-tile rows = 256B
  const int g1 = o1 ^ (((o1 >> 8) & 7) << 4);

  f32x4 nacc0 = {0.f, 0.f, 0.f, 0.f};
  f32x4 nacc1 = {0.f, 0.f, 0.f, 0.f};
  float z0 = 0.f, z1 = 0.f, z2 = 0.f, z3 = 0.f;
  float w0 = 0.f, w1 = 0.f, w2 = 0.f, w3 = 0.f;

  // prologue: stage tile 0 into kbuf[0]
  stage16((const char*)xnTb + g0, &kbuf[0][o0]);
  stage16((const char*)xnTb + g1, &kbuf[0][o1]);
  __builtin_amdgcn_sched_barrier(0);

#pragma unroll 1
  for (int t = 0; t < NT; ++t) {
    const int cur = t & 1;
    const int j0 = t * KT;

    // --- tile-t global loads FIRST (so counted vmcnt keeps prefetch alive) ---
    const float* pbase = probs + (size_t)(q0 + qf1 * 16 + lhi * 4) * HW + (j0 + kf * 16 + llo);
    float p0 = pbase[0];
    float p1 = pbase[HW];
    float p2 = pbase[2 * HW];
    float p3 = pbase[3 * HW];

    const unsigned short* xp = xcb + (size_t)(cf0 * 16 + llo) * HW + j0 + lhi * 8;
    s16x8 xb00 = *(const s16x8*)(xp);
    s16x8 xb01 = *(const s16x8*)(xp + 32);
    s16x8 xb10 = *(const s16x8*)(xp + (size_t)16 * HW);
    s16x8 xb11 = *(const s16x8*)(xp + (size_t)16 * HW + 32);
    __builtin_amdgcn_sched_barrier(0);

    // --- stage tile t+1 (wraps harmlessly at t=NT-1) ---
    {
      const char* tb = (const char*)(xnTb + (size_t)(((t + 1) & (NT - 1)) * KT) * CDIM);
      stage16(tb + g0, &kbuf[cur ^ 1][o0 - 0]);
      stage16(tb + g1, &kbuf[cur ^ 1][o1 - 1024] + 1024);
    }
    __builtin_amdgcn_sched_barrier(0);

    // wait: tile-t staging done; 10 youngest (probs4 + xb4 + stage(t+1)2) stay in flight
    asm volatile("s_waitcnt vmcnt(10)" ::: "memory");
    __builtin_amdgcn_sched_barrier(0);
    __builtin_amdgcn_s_barrier();
    __builtin_amdgcn_sched_barrier(0);

    // --- phase 1: S frag = Q . K^T ---
    f32x4 sacc = {0.f, 0.f, 0.f, 0.f};
    {
      const int row = kf * 16 + llo;
      const unsigned char* rp = &kbuf[cur][row * 256];
      const int sw = (row & 7) << 4;
#pragma unroll
      for (int kk = 0; kk < 4; ++kk) {
        s16x8 bk = *(const s16x8*)(rp + ((kk * 64 + lhi * 16) ^ sw));
        sacc = __builtin_amdgcn_mfma_f32_16x16x32_bf16(aq[kk], bk, sacc, 0, 0, 0);
      }
    }
    {
      const int jl2 = (kf * 16 + llo) * 2;
#define P1R(rr, pv, zz, ww)                                                     \
      {                                                                         \
        float e = __expf(sacc[rr]);                                             \
        zz += e;                                                                \
        float pe = e * (pv);                                                    \
        ww += pe;                                                               \
        const int ql = qf1 * 16 + lhi * 4 + rr;                                 \
        *(unsigned short*)(&pbuf[(ql * 128 + jl2) ^ ((ql & 7) << 4)]) = f2bf(pe); \
      }
      P1R(0, p0, z0, w0)
      P1R(1, p1, z1, w1)
      P1R(2, p2, z2, w2)
      P1R(3, p3, z3, w3)
#undef P1R
    }

    asm volatile("s_waitcnt lgkmcnt(0)" ::: "memory");
    __builtin_amdgcn_sched_barrier(0);
    __builtin_amdgcn_s_barrier();
    __builtin_amdgcn_sched_barrier(0);

    // --- phase 2: N += P' . X^T  (B operand straight from global, L2-hot) ---
    {
      const int qrow = qf2 * 16 + llo;
      const unsigned char* pp = &pbuf[qrow * 128];
      const int sw = (qrow & 7) << 4;
      s16x8 pa0 = *(const s16x8*)(pp + ((lhi * 16) ^ sw));
      s16x8 pa1 = *(const s16x8*)(pp + ((64 + lhi * 16) ^ sw));
      nacc0 = __builtin_amdgcn_mfma_f32_16x16x32_bf16(pa0, xb00, nacc0, 0, 0, 0);
      nacc0 = __builtin_amdgcn_mfma_f32_16x16x32_bf16(pa1, xb01, nacc0, 0, 0, 0);
      nacc1 = __builtin_amdgcn_mfma_f32_16x16x32_bf16(pa0, xb10, nacc1, 0, 0, 0);
      nacc1 = __builtin_amdgcn_mfma_f32_16x16x32_bf16(pa1, xb11, nacc1, 0, 0, 0);
    }

    asm volatile("s_waitcnt lgkmcnt(0)" ::: "memory");
    __builtin_amdgcn_sched_barrier(0);
    __builtin_amdgcn_s_barrier();
    __builtin_amdgcn_sched_barrier(0);
  }

  // drain wrap-around stage before reusing kbuf as obuf
  asm volatile("s_waitcnt vmcnt(0)" ::: "memory");
  __builtin_amdgcn_sched_barrier(0);

  // Z / Pr butterfly over the 16-lane key group -> per-query scalars
#define RED(zz, ww, rr)                                                        \
  {                                                                            \
    float z = zz, p = ww;                                                      \
    z += __shfl_xor(z, 1); p += __shfl_xor(p, 1);                              \
    z += __shfl_xor(z, 2); p += __shfl_xor(p, 2);                              \
    z += __shfl_xor(z, 4); p += __shfl_xor(p, 4);                              \
    z += __shfl_xor(z, 8); p += __shfl_xor(p, 8);                              \
    if (llo == 0) {                                                            \
      zred[kf][qf1 * 16 + lhi * 4 + rr] = z;                                   \
      prred[kf][qf1 * 16 + lhi * 4 + rr] = p;                                  \
    }                                                                          \
  }
  RED(z0, w0, 0) RED(z1, w1, 1) RED(z2, w2, 2) RED(z3, w3, 3)
#undef RED
  __syncthreads();

  if (tid < QT) {
    float zz = zred[0][tid] + zred[1][tid] + zred[2][tid] + zred[3][tid];
    float pp = prred[0][tid] + prred[1][tid] + prred[2][tid] + prred[3][tid];
    denl[tid] = pp + zz * 1e-8f;
  }
  __syncthreads();

  // epilogue: divide, LDS transpose (reuse kbuf), coalesced fp32 store
  float* obuf = (float*)&kbuf[0][0];  // [128][36] fp32 = 18KB < 32KB
#pragma unroll
  for (int r = 0; r < 4; ++r) {
    const int ql = qf2 * 16 + lhi * 4 + r;
    const float rd = 1.0f / denl[ql];
    obuf[(cf0 * 16 + llo) * 36 + ql]       = nacc0[r] * rd;
    obuf[((cf0 + 1) * 16 + llo) * 36 + ql] = nacc1[r] * rd;
  }
  __syncthreads();
  {
    const int c = tid >> 2;
    const int qq = (tid & 3) * 8;
    const float* src = obuf + c * 36 + qq;
    f32x4 v0 = *(const f32x4*)(src);
    f32x4 v1 = *(const f32x4*)(src + 4);
    float* op = out + ((size_t)(b * CDIM + c) << 12) + q0 + qq;
    *(f32x4*)(op) = v0;
    *(f32x4*)(op + 4) = v1;
  }
}

extern "C" void kernel_launch(void* const* d_in, const int* in_sizes, int n_in,
                              void* d_out, int out_size, void* d_ws, size_t ws_size,
                              hipStream_t stream) {
  (void)in_sizes; (void)n_in; (void)out_size; (void)ws_size;
  const float* embds = (const float*)d_in[0];   // (2,128,64,64) fp32
  const float* probs = (const float*)d_in[1];   // (64,64,64,64) fp32
  unsigned short* xnT = (unsigned short*)d_ws;                       // 2MB bf16
  unsigned short* xc  = xnT + (size_t)NBATCH * HW * CDIM;            // 2MB bf16
  prep_kernel<<<NBATCH * (HW / 64), 256, 0, stream>>>(embds, xnT, xc);
  glom_attn_kernel<<<NBATCH * (HW / QT), 512, 0, stream>>>(probs, xnT, xc, (float*)d_out);
}